// Round 4
// baseline (1019.623 us; speedup 1.0000x reference)
//
#include <hip/hip_runtime.h>

#define MAX_SR 3
#define TSZ 8   // TEMPLATE_SZ

// out[(((b*H+h)*W + w)*CV2 + d)*64 + e] = (int)trunc(Pzero[b, h+base+dy+ky, w+base+dx+kx])
// where d = dy*CV+dx, e = ky*8+kx, base = -(sr + TSZ/2).
// Output is int32 per element (harness reads uint8-ref outputs as np.int32).
// Thread t in [0,16) of each (b,h,w,d) writes e = 4t..4t+3 as one int4.
template<int CV>
__global__ __launch_bounds__(256) void esw_kernel(
    const float* __restrict__ x, int* __restrict__ out,
    int H, int W, int base)
{
    constexpr int CV2 = CV * CV;
    const int NW = W * CV2 * 16;              // threads per (b,h) row
    int idx = blockIdx.x * 256 + threadIdx.x; // [0, NW)
    if (idx >= NW) return;
    const int b = blockIdx.z;
    const int h = blockIdx.y;

    int t  = idx & 15;        // e-quad index
    int r  = idx >> 4;        // w*CV2 + d
    int d  = r % CV2;         // compile-time CV2 -> magic mul
    int w  = r / CV2;
    int dy = d / CV;
    int dx = d - dy * CV;
    int ky  = t >> 1;
    int kx0 = (t & 1) << 2;

    int yy  = h + base + dy + ky;
    int xx0 = w + base + dx + kx0;

    const float* __restrict__ xrow = x + ((size_t)b * H + yy) * (size_t)W;
    const bool rowok = ((unsigned)yy < (unsigned)H);

    int4 v;
    {
        int xx;
        xx = xx0 + 0; v.x = (rowok && (unsigned)xx < (unsigned)W) ? (int)xrow[xx] : 0;
        xx = xx0 + 1; v.y = (rowok && (unsigned)xx < (unsigned)W) ? (int)xrow[xx] : 0;
        xx = xx0 + 2; v.z = (rowok && (unsigned)xx < (unsigned)W) ? (int)xrow[xx] : 0;
        xx = xx0 + 3; v.w = (rowok && (unsigned)xx < (unsigned)W) ? (int)xrow[xx] : 0;
    }

    size_t o = (((size_t)b * H + h) * (size_t)NW + idx) * 4;
    *reinterpret_cast<int4*>(out + o) = v;
}

// Generic fallback (runtime cv) — same math, runtime divisions.
__global__ __launch_bounds__(256) void esw_kernel_gen(
    const float* __restrict__ x, int* __restrict__ out,
    int H, int W, int base, int cv)
{
    const int cv2 = cv * cv;
    const int NW = W * cv2 * 16;
    int idx = blockIdx.x * 256 + threadIdx.x;
    if (idx >= NW) return;
    const int b = blockIdx.z;
    const int h = blockIdx.y;

    int t  = idx & 15;
    int r  = idx >> 4;
    int d  = r % cv2;
    int w  = r / cv2;
    int dy = d / cv;
    int dx = d - dy * cv;
    int ky  = t >> 1;
    int kx0 = (t & 1) << 2;

    int yy  = h + base + dy + ky;
    int xx0 = w + base + dx + kx0;

    const float* __restrict__ xrow = x + ((size_t)b * H + yy) * (size_t)W;
    const bool rowok = ((unsigned)yy < (unsigned)H);

    int4 v;
    int xx;
    xx = xx0 + 0; v.x = (rowok && (unsigned)xx < (unsigned)W) ? (int)xrow[xx] : 0;
    xx = xx0 + 1; v.y = (rowok && (unsigned)xx < (unsigned)W) ? (int)xrow[xx] : 0;
    xx = xx0 + 2; v.z = (rowok && (unsigned)xx < (unsigned)W) ? (int)xrow[xx] : 0;
    xx = xx0 + 3; v.w = (rowok && (unsigned)xx < (unsigned)W) ? (int)xrow[xx] : 0;

    size_t o = (((size_t)b * H + h) * (size_t)NW + idx) * 4;
    *reinterpret_cast<int4*>(out + o) = v;
}

extern "C" void kernel_launch(void* const* d_in, const int* in_sizes, int n_in,
                              void* d_out, int out_size, void* d_ws, size_t ws_size,
                              hipStream_t stream)
{
    const float* x = (const float*)d_in[0];
    int* out = (int*)d_out;

    // Shapes per reference setup: (B, 1, 192, 320)
    const int H = 192, W = 320;
    int B = in_sizes[0] / (H * W);
    if (B < 1) B = 1;

    // Derive cv (= 2*sr+1) from output size: out_size = B*H*W*cv^2*64
    long cv2l = (long)out_size / ((long)in_sizes[0] * (TSZ * TSZ));
    int cv = 1;
    while ((long)(cv + 2) * (cv + 2) <= cv2l) cv += 2;
    int sr = (cv - 1) / 2;
    int base = -(sr + TSZ / 2);   // (MAX_SR - sr) - (MAX_SR + TSZ/2)

    const int NW = W * cv * cv * 16;
    dim3 grid((NW + 255) / 256, H, B);
    dim3 block(256);

    switch (cv) {
        case 1: esw_kernel<1><<<grid, block, 0, stream>>>(x, out, H, W, base); break;
        case 3: esw_kernel<3><<<grid, block, 0, stream>>>(x, out, H, W, base); break;
        case 5: esw_kernel<5><<<grid, block, 0, stream>>>(x, out, H, W, base); break;
        case 7: esw_kernel<7><<<grid, block, 0, stream>>>(x, out, H, W, base); break;
        default: esw_kernel_gen<<<grid, block, 0, stream>>>(x, out, H, W, base, cv); break;
    }
}

// Round 7
// 768.788 us; speedup vs baseline: 1.3263x; 1.3263x over previous
//
#include <hip/hip_runtime.h>

#define MAX_SR 3
#define TSZ 8   // TEMPLATE_SZ

// out[(((b*H+h)*W + w)*CV2 + d)*64 + e] = (int)Pzero[b, h+base+dy+ky, w+base+dx+kx]
// d = dy*CV+dx, e = ky*8+kx, base = -(sr + TSZ/2). Output int32 per element.
//
// LDS-staged version: block = (w-tile of 16, one h, one b). Stage the
// (CV-1+8) x (16+CV+6) input patch in LDS once, then 25 unrolled int4 stores
// per thread fed from LDS. Stores are the only HBM traffic that matters.
template<int CV>
__global__ __launch_bounds__(256) void esw_lds(
    const float* __restrict__ x, int* __restrict__ out,
    int H, int W, int base)
{
    constexpr int CV2  = CV * CV;
    constexpr int TW   = 16;
    constexpr int ROWS = CV - 1 + TSZ;            // 12 for cv=5
    constexpr int COLS = TW + CV - 1 + TSZ - 1;   // 27 for cv=5 (odd pitch -> no bank aliasing)
    __shared__ float s[ROWS * COLS];

    const int b  = blockIdx.z;
    const int h  = blockIdx.y;
    const int w0 = blockIdx.x * TW;

    // ---- stage input patch (zero-padded) ----
    const float* __restrict__ xb = x + (size_t)b * H * W;
    for (int i = threadIdx.x; i < ROWS * COLS; i += 256) {
        int r  = i / COLS;                 // compile-time COLS -> magic mul
        int c  = i - r * COLS;
        int yy = h + base + r;
        int xx = w0 + base + c;
        float v = 0.0f;
        if ((unsigned)yy < (unsigned)H && (unsigned)xx < (unsigned)W)
            v = xb[yy * W + xx];
        s[i] = v;
    }
    __syncthreads();

    // ---- emit: thread = (wl, t); t indexes the e-quad (e = 4t..4t+3) ----
    const int t   = threadIdx.x & 15;
    const int wl  = threadIdx.x >> 4;      // 0..15
    const int ky  = t >> 1;
    const int kx0 = (t & 1) << 2;
    const int w   = w0 + wl;
    if (w >= W) return;                    // no-op for exact W=320

    int* __restrict__ op = out + ((((size_t)b * H + h) * W + w) * CV2) * 64 + t * 4;
    const float* __restrict__ sp = s + ky * COLS + wl + kx0;

    #pragma unroll
    for (int d = 0; d < CV2; ++d) {
        const int dy = d / CV;             // compile-time
        const int dx = d - dy * CV;
        const float* p = sp + dy * COLS + dx;
        int4 v;
        v.x = (int)p[0];
        v.y = (int)p[1];
        v.z = (int)p[2];
        v.w = (int)p[3];
        *reinterpret_cast<int4*>(op + d * 64) = v;
    }
}

// Generic fallback (runtime cv): direct gather, correct but slower.
__global__ __launch_bounds__(256) void esw_kernel_gen(
    const float* __restrict__ x, int* __restrict__ out,
    int H, int W, int base, int cv)
{
    const int cv2 = cv * cv;
    const int NW = W * cv2 * 16;
    int idx = blockIdx.x * 256 + threadIdx.x;
    if (idx >= NW) return;
    const int b = blockIdx.z;
    const int h = blockIdx.y;

    int t  = idx & 15;
    int r  = idx >> 4;
    int d  = r % cv2;
    int w  = r / cv2;
    int dy = d / cv;
    int dx = d - dy * cv;
    int ky  = t >> 1;
    int kx0 = (t & 1) << 2;

    int yy  = h + base + dy + ky;
    int xx0 = w + base + dx + kx0;

    const float* __restrict__ xrow = x + ((size_t)b * H + yy) * (size_t)W;
    const bool rowok = ((unsigned)yy < (unsigned)H);

    int4 v;
    int xx;
    xx = xx0 + 0; v.x = (rowok && (unsigned)xx < (unsigned)W) ? (int)xrow[xx] : 0;
    xx = xx0 + 1; v.y = (rowok && (unsigned)xx < (unsigned)W) ? (int)xrow[xx] : 0;
    xx = xx0 + 2; v.z = (rowok && (unsigned)xx < (unsigned)W) ? (int)xrow[xx] : 0;
    xx = xx0 + 3; v.w = (rowok && (unsigned)xx < (unsigned)W) ? (int)xrow[xx] : 0;

    size_t o = (((size_t)b * H + h) * (size_t)NW + idx) * 4;
    *reinterpret_cast<int4*>(out + o) = v;
}

extern "C" void kernel_launch(void* const* d_in, const int* in_sizes, int n_in,
                              void* d_out, int out_size, void* d_ws, size_t ws_size,
                              hipStream_t stream)
{
    const float* x = (const float*)d_in[0];
    int* out = (int*)d_out;

    const int H = 192, W = 320;
    int B = in_sizes[0] / (H * W);
    if (B < 1) B = 1;

    // Derive cv from out_size = B*H*W*cv^2*64
    long cv2l = (long)out_size / ((long)in_sizes[0] * (TSZ * TSZ));
    int cv = 1;
    while ((long)(cv + 2) * (cv + 2) <= cv2l) cv += 2;
    int sr = (cv - 1) / 2;
    int base = -(sr + TSZ / 2);

    dim3 block(256);
    dim3 grid((W + 15) / 16, H, B);

    switch (cv) {
        case 1: esw_lds<1><<<grid, block, 0, stream>>>(x, out, H, W, base); break;
        case 3: esw_lds<3><<<grid, block, 0, stream>>>(x, out, H, W, base); break;
        case 5: esw_lds<5><<<grid, block, 0, stream>>>(x, out, H, W, base); break;
        case 7: esw_lds<7><<<grid, block, 0, stream>>>(x, out, H, W, base); break;
        default: {
            const int NW = W * cv * cv * 16;
            dim3 g2((NW + 255) / 256, H, B);
            esw_kernel_gen<<<g2, block, 0, stream>>>(x, out, H, W, base, cv);
            break;
        }
    }
}

// Round 8
// 767.860 us; speedup vs baseline: 1.3279x; 1.0012x over previous
//
#include <hip/hip_runtime.h>

#define MAX_SR 3
#define TSZ 8   // TEMPLATE_SZ

// out[(((b*H+h)*W + w)*CV2 + d)*64 + e] = (int)Pzero[b, h+base+dy+ky, w+base+dx+kx]
// d = dy*CV+dx, e = ky*8+kx, base = -(sr + TSZ/2). Output int32.
//
// LDS-staged + CONTIGUOUS-STORE version. Block = (16 w's, one h, one b),
// owning a contiguous 16*CV2*64-int output window. Iteration s of thread tid
// writes int4 index f = s*256 + tid of that window: each wave stores 1 KiB
// contiguous; the block sweeps its window sequentially in 4 KiB steps.
// The (wl, d) decode for the LDS read uses compile-time divisions (magic mul).
template<int CV>
__global__ __launch_bounds__(256) void esw_lds(
    const float* __restrict__ x, int* __restrict__ out,
    int H, int W, int base)
{
    constexpr int CV2  = CV * CV;               // 25 for cv=5
    constexpr int TW   = 16;
    constexpr int ROWS = CV - 1 + TSZ;          // 12
    constexpr int COLS = TW + CV - 1 + TSZ - 1; // 27 (odd pitch)
    constexpr int NS   = TW * CV2 * 16 / 256;   // int4-stores per thread = 25
    __shared__ float smem[ROWS * COLS];

    const int b  = blockIdx.z;
    const int h  = blockIdx.y;
    const int w0 = blockIdx.x * TW;

    // ---- stage input patch (zero-padded) ----
    const float* __restrict__ xb = x + (size_t)b * H * W;
    for (int i = threadIdx.x; i < ROWS * COLS; i += 256) {
        int r  = i / COLS;                 // compile-time COLS
        int c  = i - r * COLS;
        int yy = h + base + r;
        int xx = w0 + base + c;
        float v = 0.0f;
        if ((unsigned)yy < (unsigned)H && (unsigned)xx < (unsigned)W)
            v = xb[yy * W + xx];
        smem[i] = v;
    }
    __syncthreads();

    const int tid = threadIdx.x;
    const int t   = tid & 15;          // e-quad: e = t*4 + j
    const int hi  = tid >> 4;          // 0..15
    const int ky  = t >> 1;
    const int kx0 = (t & 1) << 2;

    int* __restrict__ ob =
        out + ((((size_t)b * H + h) * W + w0) * CV2) * 64;
    const float* __restrict__ sb = smem + ky * COLS + kx0;

    #pragma unroll
    for (int s = 0; s < NS; ++s) {
        // flat int4 index f = s*256 + tid -> r = f>>4 = s*16 + hi
        int r  = s * 16 + hi;
        int wl = r / CV2;              // compile-time CV2 -> magic mul
        int d  = r - wl * CV2;
        int dy = d / CV;               // compile-time CV
        int dx = d - dy * CV;
        const float* p = sb + dy * COLS + dx + wl;
        int4 v;
        v.x = (int)p[0];
        v.y = (int)p[1];
        v.z = (int)p[2];
        v.w = (int)p[3];
        *reinterpret_cast<int4*>(ob + (size_t)(s * 256 + tid) * 4) = v;
    }
}

// Generic fallback (runtime cv, or W not a multiple of 16): direct gather.
__global__ __launch_bounds__(256) void esw_kernel_gen(
    const float* __restrict__ x, int* __restrict__ out,
    int H, int W, int base, int cv)
{
    const int cv2 = cv * cv;
    const int NW = W * cv2 * 16;
    int idx = blockIdx.x * 256 + threadIdx.x;
    if (idx >= NW) return;
    const int b = blockIdx.z;
    const int h = blockIdx.y;

    int t  = idx & 15;
    int r  = idx >> 4;
    int d  = r % cv2;
    int w  = r / cv2;
    int dy = d / cv;
    int dx = d - dy * cv;
    int ky  = t >> 1;
    int kx0 = (t & 1) << 2;

    int yy  = h + base + dy + ky;
    int xx0 = w + base + dx + kx0;

    const float* __restrict__ xrow = x + ((size_t)b * H + yy) * (size_t)W;
    const bool rowok = ((unsigned)yy < (unsigned)H);

    int4 v;
    int xx;
    xx = xx0 + 0; v.x = (rowok && (unsigned)xx < (unsigned)W) ? (int)xrow[xx] : 0;
    xx = xx0 + 1; v.y = (rowok && (unsigned)xx < (unsigned)W) ? (int)xrow[xx] : 0;
    xx = xx0 + 2; v.z = (rowok && (unsigned)xx < (unsigned)W) ? (int)xrow[xx] : 0;
    xx = xx0 + 3; v.w = (rowok && (unsigned)xx < (unsigned)W) ? (int)xrow[xx] : 0;

    size_t o = (((size_t)b * H + h) * (size_t)NW + idx) * 4;
    *reinterpret_cast<int4*>(out + o) = v;
}

extern "C" void kernel_launch(void* const* d_in, const int* in_sizes, int n_in,
                              void* d_out, int out_size, void* d_ws, size_t ws_size,
                              hipStream_t stream)
{
    const float* x = (const float*)d_in[0];
    int* out = (int*)d_out;

    const int H = 192, W = 320;
    int B = in_sizes[0] / (H * W);
    if (B < 1) B = 1;

    // Derive cv from out_size = B*H*W*cv^2*64
    long cv2l = (long)out_size / ((long)in_sizes[0] * (TSZ * TSZ));
    int cv = 1;
    while ((long)(cv + 2) * (cv + 2) <= cv2l) cv += 2;
    int sr = (cv - 1) / 2;
    int base = -(sr + TSZ / 2);

    dim3 block(256);

    if ((W & 15) == 0 && (cv == 1 || cv == 3 || cv == 5 || cv == 7)) {
        dim3 grid(W / 16, H, B);
        switch (cv) {
            case 1: esw_lds<1><<<grid, block, 0, stream>>>(x, out, H, W, base); break;
            case 3: esw_lds<3><<<grid, block, 0, stream>>>(x, out, H, W, base); break;
            case 5: esw_lds<5><<<grid, block, 0, stream>>>(x, out, H, W, base); break;
            case 7: esw_lds<7><<<grid, block, 0, stream>>>(x, out, H, W, base); break;
        }
    } else {
        const int NW = W * cv * cv * 16;
        dim3 g2((NW + 255) / 256, H, B);
        esw_kernel_gen<<<g2, block, 0, stream>>>(x, out, H, W, base, cv);
    }
}